// Round 6
// baseline (204.908 us; speedup 1.0000x reference)
//
#include <hip/hip_runtime.h>

#define U_   2048
#define T_   200
#define S_   10
#define K_   20
#define H_   16
#define DU_  32
#define DE_  32
#define DIN_ 264   // 32 + 11 + 220 + 1

#define POSB 64    // positions per block == threads per block
#define ROWB 800   // f row bytes
#define RPAD 808   // padded LDS row stride (202 words == 10 mod 32 -> 4-way read floor)

// ---------------------------------------------------------------------------
// Kernel 1: pre[pos,h] = b_rnn[h] + x[pos,:] . Wx[:,h]
// Block = 64 threads = 64 positions = ONE CONTIGUOUS 51200B f-image.
// Stage: thread t loads granule i*64+t (wave reads 1KB linear per instr ==
// the fill-kernel pattern that measured 6.8 TB/s), writes to 808B-padded LDS
// rows (reg-staged; global_load_lds can't pad, m104). Compute: own row via
// ds_read_b64 (4-way bank floor). Weights wave-uniform -> SGPR (R4-proven).
// ---------------------------------------------------------------------------
__global__ __launch_bounds__(64) void k_pre(
    const float* __restrict__ q, const float* __restrict__ f,
    const int* __restrict__ docid, const float* __restrict__ ct,
    const float* __restrict__ emb, const float* __restrict__ Wx,
    const float* __restrict__ brnn, float* __restrict__ pre)
{
    __shared__ __align__(16) char lbuf[POSB * RPAD];   // 51712 B
    const int t = threadIdx.x;
    const int blk = blockIdx.x;                        // grid 6400 exact
    const int idx = blk * POSB + t;

    const char* src = (const char*)f + (size_t)blk * (POSB * ROWB);

    float4 ga[10], gb[10];

    // ---- preload staging round 0 (granules 0..639, linear) ----
#pragma unroll
    for (int i = 0; i < 10; ++i)
        ga[i] = *(const float4*)(src + (size_t)(i * 64 + t) * 16);

    // ---- issue all direct loads early (latency overlaps staging) ----
    const int did = docid[idx];
    float4 e[8];
    const float4* e4 = (const float4*)(emb + (size_t)did * DE_);
#pragma unroll
    for (int r = 0; r < 8; ++r) e[r] = e4[r];
    float2 qv[5];
    const float2* q2 = (const float2*)(q + (size_t)idx * S_);
#pragma unroll
    for (int r = 0; r < 5; ++r) qv[r] = q2[r];
    const float cv = ct[idx];

    // ---- staging rounds: issue r+1, write r (double reg bank, static idx) ----
#pragma unroll
    for (int r = 0; r < 5; ++r) {
        if (r < 4) {
            if ((r & 1) == 0) {
#pragma unroll
                for (int i = 0; i < 10; ++i)
                    gb[i] = *(const float4*)(src + (size_t)((r + 1) * 640 + i * 64 + t) * 16);
            } else {
#pragma unroll
                for (int i = 0; i < 10; ++i)
                    ga[i] = *(const float4*)(src + (size_t)((r + 1) * 640 + i * 64 + t) * 16);
            }
        }
#pragma unroll
        for (int i = 0; i < 10; ++i) {
            const int g = r * 640 + i * 64 + t;
            const int pos = g / 50;                  // compiler magic-div
            const int off = pos * RPAD + (g - pos * 50) * 16;
            const float4 v = ((r & 1) == 0) ? ga[i] : gb[i];
            *(float2*)(lbuf + off)     = make_float2(v.x, v.y);
            *(float2*)(lbuf + off + 8) = make_float2(v.z, v.w);
        }
    }

    // ---- emb / ctime / q accumulation (regs already in flight) ----
    float acc[H_];
#pragma unroll
    for (int h = 0; h < H_; ++h) acc[h] = brnn[h];   // uniform -> s_load

#pragma unroll
    for (int r = 0; r < 8; ++r) {
        const float4 v = e[r];
        const float* w = Wx + (r * 4) * H_;
#pragma unroll
        for (int h = 0; h < H_; ++h)
            acc[h] += v.x * w[h] + v.y * w[h + 16] + v.z * w[h + 32] + v.w * w[h + 48];
    }
    {
        const float* w = Wx + (DIN_ - 1) * H_;
#pragma unroll
        for (int h = 0; h < H_; ++h) acc[h] += cv * w[h];
    }
#pragma unroll
    for (int j = 0; j < 5; ++j) {
        const float2 v = qv[j];
        const float* w = Wx + (DE_ + 2 * j) * H_;
#pragma unroll
        for (int h = 0; h < H_; ++h)
            acc[h] += v.x * w[h] + v.y * w[h + 16];
    }

    __syncthreads();   // staging visible (single wave per block: cheap)

    // ---- f part: own padded row, 100 x ds_read_b64, Wx rows 43+2k ----
    {
        const float2* row = (const float2*)(lbuf + t * RPAD);
#pragma unroll 10
        for (int k = 0; k < 100; ++k) {
            const float2 v = row[k];
            const float* w = Wx + (43 + 2 * k) * H_;   // uniform -> s_load
#pragma unroll
            for (int h = 0; h < H_; ++h)
                acc[h] += v.x * w[h] + v.y * w[h + 16];
        }
    }

    // ---- store ----
    float4* o = (float4*)(pre + (size_t)idx * H_);
    o[0] = make_float4(acc[0], acc[1], acc[2], acc[3]);
    o[1] = make_float4(acc[4], acc[5], acc[6], acc[7]);
    o[2] = make_float4(acc[8], acc[9], acc[10], acc[11]);
    o[3] = make_float4(acc[12], acc[13], acc[14], acc[15]);
}

// ---------------------------------------------------------------------------
// Kernel 2: sequential RNN scan per user (16 lanes = 16 h-components),
// fused LeakyReLU + Dense(32).  (unchanged)
// ---------------------------------------------------------------------------
__device__ __forceinline__ float tanh_fast(float x) {
    float e = __expf(2.f * x);
    return 1.f - 2.f / (e + 1.f);
}

__global__ __launch_bounds__(64) void k_rnn(
    const float* __restrict__ pre, const int* __restrict__ docid,
    const float* __restrict__ Wh, const float* __restrict__ Wd,
    const float* __restrict__ bd, float* __restrict__ out)
{
    const int tid = threadIdx.x;
    const int l = tid & 15;
    const int u = (blockIdx.x * 64 + tid) >> 4;

    const float* prow = pre + (size_t)u * T_ * H_;
    const int* drow = docid + (size_t)u * T_;

    float wh[16];
#pragma unroll
    for (int k = 0; k < 16; ++k) wh[k] = Wh[((l ^ k) << 4) | l];

    float h = 0.f;

    float pb0 = prow[0 * H_ + l], pb1 = prow[1 * H_ + l],
          pb2 = prow[2 * H_ + l], pb3 = prow[3 * H_ + l];
    int   m0 = drow[0], m1 = drow[1], m2 = drow[2], m3 = drow[3];

    for (int tb = 0; tb < T_; tb += 4) {
#pragma unroll
        for (int s = 0; s < 4; ++s) {
            float p; int m;
            if      (s == 0) { p = pb0; m = m0; }
            else if (s == 1) { p = pb1; m = m1; }
            else if (s == 2) { p = pb2; m = m2; }
            else             { p = pb3; m = m3; }

            int tn = tb + 4 + s; if (tn > T_ - 1) tn = T_ - 1;
            float pn = prow[tn * H_ + l];
            int   mn = drow[tn];
            if      (s == 0) { pb0 = pn; m0 = mn; }
            else if (s == 1) { pb1 = pn; m1 = mn; }
            else if (s == 2) { pb2 = pn; m2 = mn; }
            else             { pb3 = pn; m3 = mn; }

            float a0 = p, a1 = 0.f, a2 = 0.f, a3 = 0.f;
#pragma unroll
            for (int k = 0; k < 16; k += 4) {
                a0 += __shfl_xor(h, k + 0, 16) * wh[k + 0];
                a1 += __shfl_xor(h, k + 1, 16) * wh[k + 1];
                a2 += __shfl_xor(h, k + 2, 16) * wh[k + 2];
                a3 += __shfl_xor(h, k + 3, 16) * wh[k + 3];
            }
            float accv = (a0 + a1) + (a2 + a3);
            float th = tanh_fast(accv);
            h = (m != 0) ? th : h;
        }
    }

    float a = (h >= 0.f) ? h : 0.3f * h;

    float wd0[16], wd1[16];
#pragma unroll
    for (int k = 0; k < 16; ++k) {
        int j = l ^ k;
        wd0[k] = Wd[j * DU_ + l];
        wd1[k] = Wd[j * DU_ + l + 16];
    }
    float o0 = bd[l], o1 = bd[l + 16];
#pragma unroll
    for (int k = 0; k < 16; ++k) {
        float av = __shfl_xor(a, k, 16);
        o0 += av * wd0[k];
        o1 += av * wd1[k];
    }
    out[(size_t)u * DU_ + l] = o0;
    out[(size_t)u * DU_ + l + 16] = o1;
}

// ---------------------------------------------------------------------------
extern "C" void kernel_launch(void* const* d_in, const int* in_sizes, int n_in,
                              void* d_out, int out_size, void* d_ws, size_t ws_size,
                              hipStream_t stream) {
    const float* q     = (const float*)d_in[0];
    const float* f     = (const float*)d_in[1];
    const int*   docid = (const int*)  d_in[2];
    const float* ct    = (const float*)d_in[3];
    const float* emb   = (const float*)d_in[4];
    const float* Wx    = (const float*)d_in[5];
    const float* Wh    = (const float*)d_in[6];
    const float* brnn  = (const float*)d_in[7];
    const float* Wd    = (const float*)d_in[8];
    const float* bd    = (const float*)d_in[9];
    float* out = (float*)d_out;

    float* pre = (float*)d_ws;                   // U*T*H floats = 26.2 MB

    k_pre<<<(U_ * T_) / POSB, POSB, 0, stream>>>(q, f, docid, ct, emb, Wx, brnn, pre);
    k_rnn<<<(U_ * H_) / 64, 64, 0, stream>>>(pre, docid, Wh, Wd, bd, out);
}